// Round 9
// baseline (410.268 us; speedup 1.0000x reference)
//
#include <hip/hip_runtime.h>
#include <cstdint>

#define N_NODES 100000
#define N_EDGES 1600000
#define R_REL   5
#define NBASIS  2
#define B_START 512
#define PART_SZ 12500     // 8 * 12500 = 100000 (gath0 swizzle)
#define NBUCK   256
#define BUCK_SZ 391       // 256 * 391 = 100096 >= 100000
#define EPB     6250      // edges per block in cnt/scat (256 * 6250 = 1.6M)
#define STAGE_CAP 7000    // bucket edge-count mean 6256, sd ~79
#define UNR     32        // flat-unroll edge cap (P[deg>32] ~ 1e-4)

typedef __attribute__((ext_vector_type(8))) short short8;
typedef __attribute__((ext_vector_type(4))) float f32x4;
typedef _Float16 half8 __attribute__((ext_vector_type(8)));
typedef unsigned uint32x2 __attribute__((ext_vector_type(2)));

__device__ __forceinline__ unsigned short f2bf(float f) {
    unsigned u = __float_as_uint(f);
    unsigned r = (u + 0x7FFF + ((u >> 16) & 1)) >> 16;  // RNE
    return (unsigned short)r;
}
__device__ __forceinline__ float bf2f(unsigned short u) {
    return __uint_as_float(((unsigned)u) << 16);
}
__device__ __forceinline__ unsigned short f2h(float f) {
    _Float16 h = (_Float16)f;                            // RNE
    return __builtin_bit_cast(unsigned short, h);
}

// ---------------- scatter-free CSR build ------------------------------------

__global__ __launch_bounds__(256) void k_cntb(
    const int* __restrict__ ei, int* __restrict__ bhist) {
    __shared__ int lh[NBUCK];
    int tid = threadIdx.x;
    lh[tid] = 0;
    __syncthreads();
    int base = blockIdx.x * EPB;
    for (int j = tid; j < EPB; j += 256) {
        int dst = ei[N_EDGES + base + j];
        atomicAdd(&lh[dst / BUCK_SZ], 1);
    }
    __syncthreads();
    bhist[blockIdx.x * NBUCK + tid] = lh[tid];
}

__global__ __launch_bounds__(256) void k_colscan(
    int* __restrict__ bhist, int* __restrict__ colsum) {
    __shared__ int s[256];
    int b = blockIdx.x, i = threadIdx.x;
    int v = bhist[i * NBUCK + b];
    s[i] = v;
    __syncthreads();
    for (int o = 1; o < 256; o <<= 1) {
        int t = (i >= o) ? s[i - o] : 0;
        __syncthreads();
        s[i] += t;
        __syncthreads();
    }
    bhist[i * NBUCK + b] = s[i] - v;
    if (i == 255) colsum[b] = s[255];
}

__global__ __launch_bounds__(256) void k_tiny(
    const int* __restrict__ colsum, int* __restrict__ bbase) {
    __shared__ int s[256];
    int i = threadIdx.x;
    int v = colsum[i];
    s[i] = v;
    __syncthreads();
    for (int o = 1; o < 256; o <<= 1) {
        int t = (i >= o) ? s[i - o] : 0;
        __syncthreads();
        s[i] += t;
        __syncthreads();
    }
    bbase[i] = s[i] - v;
    if (i == 255) bbase[NBUCK] = s[255];
}

// record = src | et<<17 | dst_local<<20
__global__ __launch_bounds__(256) void k_scat(
    const int* __restrict__ ei, const int* __restrict__ et,
    const int* __restrict__ bhist, const int* __restrict__ bbase,
    int* __restrict__ arena) {
    __shared__ int lc[NBUCK];
    int tid = threadIdx.x;
    lc[tid] = bhist[blockIdx.x * NBUCK + tid] + bbase[tid];
    __syncthreads();
    int base = blockIdx.x * EPB;
    for (int j = tid; j < EPB; j += 256) {
        int e   = base + j;
        int src = ei[e];
        int dst = ei[N_EDGES + e];
        int t   = et[e];
        int bk  = dst / BUCK_SZ;
        int dl  = dst - bk * BUCK_SZ;
        int pos = atomicAdd(&lc[bk], 1);
        arena[pos] = src | (t << 17) | (dl << 20);
    }
}

// builds (dst, et)-sorted CSR: pk_m = src per edge, degpk = packed 6-bit
// per-(dst,et) counts, nv5 = 1/max(cnt,1).
__global__ __launch_bounds__(256) void k_build(
    const int* __restrict__ arena, const int* __restrict__ bbase,
    int* __restrict__ off, int* __restrict__ pk_m, float* __restrict__ nv5,
    unsigned* __restrict__ degpk) {
    __shared__ int deg5[BUCK_SZ * R_REL];
    __shared__ int loff[BUCK_SZ + 1];
    __shared__ int cur5[BUCK_SZ * R_REL];
    __shared__ int stg[STAGE_CAP];
    __shared__ int tsum[256];
    int b = blockIdx.x, tid = threadIdx.x;
    int base = bbase[b], end = bbase[b + 1];
    int count = end - base;
    for (int i = tid; i < BUCK_SZ * R_REL; i += 256) deg5[i] = 0;
    __syncthreads();
    for (int i = tid; i < count; i += 256) {
        int r  = arena[base + i];
        int dl = ((unsigned)r) >> 20;
        int t  = (r >> 17) & 7;
        atomicAdd(&deg5[dl * R_REL + t], 1);
    }
    __syncthreads();
    for (int dl = tid; dl < BUCK_SZ; dl += 256) {
        loff[dl] = deg5[dl * R_REL + 0] + deg5[dl * R_REL + 1] +
                   deg5[dl * R_REL + 2] + deg5[dl * R_REL + 3] +
                   deg5[dl * R_REL + 4];
    }
    __syncthreads();
    int d0 = 2 * tid, d1 = 2 * tid + 1;
    int va = (d0 < BUCK_SZ) ? loff[d0] : 0;
    int vb = (d1 < BUCK_SZ) ? loff[d1] : 0;
    tsum[tid] = va + vb;
    __syncthreads();
    for (int o = 1; o < 256; o <<= 1) {
        int v = (tid >= o) ? tsum[tid - o] : 0;
        __syncthreads();
        tsum[tid] += v;
        __syncthreads();
    }
    int pre = tsum[tid] - (va + vb);
    if (d0 < BUCK_SZ) loff[d0] = pre;
    if (d1 < BUCK_SZ) loff[d1] = pre + va;
    __syncthreads();
    for (int dl = tid; dl < BUCK_SZ; dl += 256) {
        int nn = b * BUCK_SZ + dl;
        int run = loff[dl];
        unsigned dp = 0;
#pragma unroll
        for (int t = 0; t < R_REL; t++) {
            cur5[dl * R_REL + t] = run;
            int c = deg5[dl * R_REL + t];
            run += c;
            int cc = c > 63 ? 63 : c;
            dp |= ((unsigned)cc) << (6 * t);
        }
        if (nn < N_NODES) {
            off[nn]   = base + loff[dl];
            degpk[nn] = dp;
#pragma unroll
            for (int t = 0; t < R_REL; t++) {
                int c = deg5[dl * R_REL + t];
                nv5[nn * R_REL + t] = 1.0f / (float)(c > 0 ? c : 1);
            }
        }
    }
    if (b == NBUCK - 1 && tid == 0) off[N_NODES] = N_EDGES;
    __syncthreads();
    for (int i = tid; i < count; i += 256) {
        int r  = arena[base + i];
        int dl = ((unsigned)r) >> 20;
        int t  = (r >> 17) & 7;
        int rk = atomicAdd(&cur5[dl * R_REL + t], 1);
        if (rk < STAGE_CAP) stg[rk] = r;
    }
    __syncthreads();
    for (int i = tid; i < count; i += 256) {
        int r = stg[i < STAGE_CAP ? i : STAGE_CAP - 1];
        pk_m[base + i] = r & 0x1FFFF;     // src only; et implied by sort
    }
}

// ---------------- weight fragment prep (once, 4 blocks) ---------------------

__global__ __launch_bounds__(256) void k_wprep(
    const float* __restrict__ basis, const float* __restrict__ comp,
    const float* __restrict__ root,  const float* __restrict__ basis0,
    const float* __restrict__ comp0, const float* __restrict__ root0,
    unsigned short* __restrict__ wfh, unsigned short* __restrict__ wfr,
    unsigned short* __restrict__ wf0) {
    __shared__ float lw[5120];
    int tid = threadIdx.x;
    int l = blockIdx.x;
    if (l < 3) {
        for (int idx = tid; idx < 5120; idx += 256) {
            int r = idx >> 10, rem = idx & 1023, i = rem >> 5, o = rem & 31;
            lw[idx] = comp[l * 10 + r * 2 + 0] * basis[l * 2048 + i * 32 + o]
                    + comp[l * 10 + r * 2 + 1] * basis[l * 2048 + 1024 + i * 32 + o];
        }
        __syncthreads();
        for (int idx = tid; idx < 5120; idx += 256) {
            int ot = idx / 2560, rem = idx % 2560;
            int s = rem >> 9, ln = (rem >> 3) & 63, j = idx & 7;
            int o = ot * 16 + (ln & 15), kk = (ln >> 4) * 8 + j;
            wfh[l * 5120 + idx] = f2h(lw[s * 1024 + kk * 32 + o]);
        }
        for (int idx = tid; idx < 2048; idx += 256) {
            int ot = idx >> 10, s = (idx >> 9) & 1, ln = (idx >> 3) & 63, j = idx & 7;
            int o = ot * 16 + (ln & 15), kk = (ln >> 4) * 8 + j;
            float val = root[l * 1024 + kk * 32 + o];
            unsigned short hi = f2bf(val);
            wfr[l * 2048 + idx] = s ? f2bf(val - bf2f(hi)) : hi;
        }
    } else {
        for (int idx = tid; idx < 1024; idx += 256) {
            int k = idx >> 5, o = idx & 31;
            float val = 0.f;
            if (k < 20) {
                int r = k >> 2, i = k & 3;
                val = comp0[r * 2 + 0] * basis0[i * 32 + o]
                    + comp0[r * 2 + 1] * basis0[128 + i * 32 + o];
            } else if (k < 24) val = root0[(k - 20) * 32 + o];
            lw[idx] = val;
        }
        __syncthreads();
        for (int idx = tid; idx < 1024; idx += 256) {
            int ot = idx >> 9, ln = (idx >> 3) & 63, j = idx & 7;
            int o = ot * 16 + (ln & 15), kk = (ln >> 4) * 8 + j;
            wf0[idx] = f2h(lw[kk * 32 + o]);
        }
    }
}

// ---------------- layer-0 input prep: hb0[n][4] = bf16(x) ------------------

__global__ __launch_bounds__(256) void k_cvt0(
    const float* __restrict__ x, unsigned short* __restrict__ hb0) {
    int n = blockIdx.x * 256 + threadIdx.x;
    if (n >= N_NODES) return;
    float4 xv = *(const float4*)(x + (size_t)n * 4);
    unsigned short h0 = f2bf(xv.x), h1 = f2bf(xv.y), h2 = f2bf(xv.z), h3 = f2bf(xv.w);
    unsigned long long ph = (unsigned long long)h0 | ((unsigned long long)h1 << 16)
                          | ((unsigned long long)h2 << 32) | ((unsigned long long)h3 << 48);
    *(unsigned long long*)(hb0 + (size_t)n * 4) = ph;
}

// ---------------- gather (layers 1-3): flat-unroll, max MLP -----------------
// 8 lanes per node (cpos = 4-ch chunk of the 64B row). The node's WHOLE edge
// list (all 5 segments) is one flat unrolled stream: 32 independent pk_m
// nt-loads, then 32 independent row gathers — ONE latency round-trip per
// wave instead of ~6 serial per-segment chains (the invariant all previous
// 48-54us variants shared). Relation separation via position-masked FMAs
// (w_r = nv_r iff B_r <= k < B_{r+1}) into 5 static accumulators.
// Remainder loop covers deg > 32 (P ~ 1e-4 per node).

__global__ __launch_bounds__(256) void k_gath32(
    const unsigned short* __restrict__ hb, const int* __restrict__ pk_m,
    const float* __restrict__ nv5, const unsigned* __restrict__ degpk,
    const int* __restrict__ off, unsigned short* __restrict__ agg) {
    int tid = threadIdx.x;
    int n = blockIdx.x * 32 + (tid >> 3);      // 3125 blocks exact
    int cpos = tid & 7;                        // uint2 (4 ch) within 64B row
    const uint32x2* __restrict__ hb2 = (const uint32x2*)hb;

    int e0 = off[n];
    unsigned dp = degpk[n];
    int b1 = dp & 63;
    int b2 = b1 + ((dp >> 6) & 63);
    int b3 = b2 + ((dp >> 12) & 63);
    int b4 = b3 + ((dp >> 18) & 63);
    int deg = b4 + ((dp >> 24) & 63);
    float nv0 = nv5[n * R_REL + 0];
    float nv1 = nv5[n * R_REL + 1];
    float nv2 = nv5[n * R_REL + 2];
    float nv3 = nv5[n * R_REL + 3];
    float nv4 = nv5[n * R_REL + 4];

    int m[UNR];
#pragma unroll
    for (int k = 0; k < UNR; k++) {
        m[k] = 0;
        if (k < deg) m[k] = __builtin_nontemporal_load(pk_m + e0 + k);
    }

    float ax[R_REL], ay[R_REL], az[R_REL], aw[R_REL];
#pragma unroll
    for (int r = 0; r < R_REL; r++) { ax[r] = 0.f; ay[r] = 0.f; az[r] = 0.f; aw[r] = 0.f; }

#pragma unroll
    for (int k = 0; k < UNR; k++) {
        if (k < deg) {
            uint32x2 u = hb2[(size_t)m[k] * 8 + cpos];
            float vx = __uint_as_float(u.x << 16);
            float vy = __uint_as_float(u.x & 0xFFFF0000u);
            float vz = __uint_as_float(u.y << 16);
            float vw = __uint_as_float(u.y & 0xFFFF0000u);
            float w0 = (k < b1) ? nv0 : 0.f;
            float w1 = (k >= b1 && k < b2) ? nv1 : 0.f;
            float w2 = (k >= b2 && k < b3) ? nv2 : 0.f;
            float w3 = (k >= b3 && k < b4) ? nv3 : 0.f;
            float w4 = (k >= b4) ? nv4 : 0.f;
            ax[0] += w0 * vx; ay[0] += w0 * vy; az[0] += w0 * vz; aw[0] += w0 * vw;
            ax[1] += w1 * vx; ay[1] += w1 * vy; az[1] += w1 * vz; aw[1] += w1 * vw;
            ax[2] += w2 * vx; ay[2] += w2 * vy; az[2] += w2 * vz; aw[2] += w2 * vw;
            ax[3] += w3 * vx; ay[3] += w3 * vy; az[3] += w3 * vz; aw[3] += w3 * vw;
            ax[4] += w4 * vx; ay[4] += w4 * vy; az[4] += w4 * vz; aw[4] += w4 * vw;
        }
    }
    for (int k = UNR; k < deg; k++) {        // rare tail
        int mk = __builtin_nontemporal_load(pk_m + e0 + k);
        uint32x2 u = hb2[(size_t)mk * 8 + cpos];
        float vx = __uint_as_float(u.x << 16);
        float vy = __uint_as_float(u.x & 0xFFFF0000u);
        float vz = __uint_as_float(u.y << 16);
        float vw = __uint_as_float(u.y & 0xFFFF0000u);
        float w0 = (k < b1) ? nv0 : 0.f;
        float w1 = (k >= b1 && k < b2) ? nv1 : 0.f;
        float w2 = (k >= b2 && k < b3) ? nv2 : 0.f;
        float w3 = (k >= b3 && k < b4) ? nv3 : 0.f;
        float w4 = (k >= b4) ? nv4 : 0.f;
        ax[0] += w0 * vx; ay[0] += w0 * vy; az[0] += w0 * vz; aw[0] += w0 * vw;
        ax[1] += w1 * vx; ay[1] += w1 * vy; az[1] += w1 * vz; aw[1] += w1 * vw;
        ax[2] += w2 * vx; ay[2] += w2 * vy; az[2] += w2 * vz; aw[2] += w2 * vw;
        ax[3] += w3 * vx; ay[3] += w3 * vy; az[3] += w3 * vz; aw[3] += w3 * vw;
        ax[4] += w4 * vx; ay[4] += w4 * vy; az[4] += w4 * vz; aw[4] += w4 * vw;
    }
#pragma unroll
    for (int r = 0; r < R_REL; r++) {
        uint32x2 pk;
        pk.x = (unsigned)f2h(ax[r]) | ((unsigned)f2h(ay[r]) << 16);
        pk.y = (unsigned)f2h(az[r]) | ((unsigned)f2h(aw[r]) << 16);
        __builtin_nontemporal_store(pk,
            (uint32x2*)(agg + (size_t)n * 160 + r * 32 + cpos * 4));
    }
}

// gather layer 0 (IN=4): R4's verified wave-parallel version. lane =
// slot(4b)*2 + cpos(1b); 16 edges in flight, uint (2 bf16 ch) loads.
// Also fills x (f16) + zero pad cols 20-31 of the [n][32] A-row.

__global__ __launch_bounds__(256) void k_gath0(
    const unsigned short* __restrict__ hb0, const float* __restrict__ x,
    const int* __restrict__ pk_m, const float* __restrict__ nv5,
    const unsigned* __restrict__ degpk, const int* __restrict__ off,
    unsigned short* __restrict__ a0v) {
    int tid  = threadIdx.x;
    int lane32 = tid & 31;
    int sub  = tid >> 5;
    int part  = blockIdx.x & 7;
    int local = (blockIdx.x >> 3) * 8 + sub;
    if (local >= PART_SZ) return;
    int n = part * PART_SZ + local;
    int cpos = lane32 & 1;
    int slot = lane32 >> 1;
    const unsigned* __restrict__ hb32 = (const unsigned*)hb0;

    int e0 = off[n];
    unsigned dp = degpk[n];
    int chunkbase = e0;
    int mreg = (chunkbase + lane32 < N_EDGES)
             ? __builtin_nontemporal_load(pk_m + chunkbase + lane32) : 0;
    int e = e0;
#pragma unroll
    for (int r = 0; r < R_REL; r++) {
        int cnt = (int)((dp >> (6 * r)) & 63u);
        float nv = nv5[n * R_REL + r];
        float p0 = 0.f, p1 = 0.f;
        for (int kb = 0; kb < cnt; kb += 16) {
            if (e + kb + 15 >= chunkbase + 32) {
                chunkbase = e + kb;
                mreg = (chunkbase + lane32 < N_EDGES)
                     ? __builtin_nontemporal_load(pk_m + chunkbase + lane32) : 0;
            }
            int kq = kb + slot;
            int mq = __shfl(mreg, e + kq - chunkbase, 32);
            unsigned u = hb32[(size_t)mq * 2 + cpos];
            float msk = (kq < cnt) ? nv : 0.f;
            p0 += msk * __uint_as_float(u << 16);
            p1 += msk * __uint_as_float(u & 0xFFFF0000u);
        }
        e += cnt;
        p0 += __shfl_xor(p0, 2, 32); p0 += __shfl_xor(p0, 4, 32);
        p0 += __shfl_xor(p0, 8, 32); p0 += __shfl_xor(p0, 16, 32);
        p1 += __shfl_xor(p1, 2, 32); p1 += __shfl_xor(p1, 4, 32);
        p1 += __shfl_xor(p1, 8, 32); p1 += __shfl_xor(p1, 16, 32);
        if (slot == 0) {
            unsigned pk = (unsigned)f2h(p0) | ((unsigned)f2h(p1) << 16);
            *(unsigned*)(a0v + (size_t)n * 32 + r * 4 + cpos * 2) = pk;
        }
    }
    if (lane32 < 12) {
        float xv = (lane32 < 4) ? x[(size_t)n * 4 + lane32] : 0.f;
        a0v[(size_t)n * 32 + 20 + lane32] = (lane32 < 4) ? f2h(xv) : (unsigned short)0;
    }
}

// ---------------- dense relation transform via MFMA -------------------------
// h[n][o] = tanh( sum_r agg_r W_r (f16) + hb_prev root (double-bf16) + bias ).
// A-frag: row = lane%16, k = (lane/16)*8+j.  C: col = lane%16,
// row = (lane/16)*4+reg.  In-place hbuf write is race-free (wave-local tile).

__global__ __launch_bounds__(256) void k_gemm(
    const unsigned short* __restrict__ agg, const unsigned short* __restrict__ hbin,
    const unsigned short* __restrict__ wfhl, const unsigned short* __restrict__ wfrl,
    const float* __restrict__ biasL, float* __restrict__ h,
    unsigned short* __restrict__ hbout) {
    int tid = threadIdx.x;
    int wid = tid >> 6, lane = tid & 63;
    int tile = blockIdx.x * 4 + wid;
    if (tile >= N_NODES / 16) return;
    int n0 = tile * 16;
    int row = lane & 15, kg = lane >> 4;
    const half8* ar = (const half8*)(agg + (size_t)(n0 + row) * 160 + kg * 8);
    const half8* wh = (const half8*)wfhl;
    const short8* wr = (const short8*)wfrl;
    short8 hbf = *(const short8*)(hbin + (size_t)(n0 + row) * 32 + kg * 8);
    f32x4 c0 = {0.f, 0.f, 0.f, 0.f}, c1 = {0.f, 0.f, 0.f, 0.f};
#pragma unroll
    for (int s = 0; s < 5; s++) {
        half8 a = __builtin_nontemporal_load(&ar[s * 4]);
        c0 = __builtin_amdgcn_mfma_f32_16x16x32_f16(a, wh[s * 64 + lane], c0, 0, 0, 0);
        c1 = __builtin_amdgcn_mfma_f32_16x16x32_f16(a, wh[320 + s * 64 + lane], c1, 0, 0, 0);
    }
    c0 = __builtin_amdgcn_mfma_f32_16x16x32_bf16(hbf, wr[lane], c0, 0, 0, 0);
    c0 = __builtin_amdgcn_mfma_f32_16x16x32_bf16(hbf, wr[64 + lane], c0, 0, 0, 0);
    c1 = __builtin_amdgcn_mfma_f32_16x16x32_bf16(hbf, wr[128 + lane], c1, 0, 0, 0);
    c1 = __builtin_amdgcn_mfma_f32_16x16x32_bf16(hbf, wr[192 + lane], c1, 0, 0, 0);
    float b0 = biasL[row], b1 = biasL[16 + row];
#pragma unroll
    for (int i = 0; i < 4; i++) {
        int n = n0 + kg * 4 + i;
        float t0 = tanhf(c0[i] + b0);
        float t1 = tanhf(c1[i] + b1);
        h[(size_t)n * 32 + row]      = t0;
        h[(size_t)n * 32 + 16 + row] = t1;
        hbout[(size_t)n * 32 + row]      = f2bf(t0);
        hbout[(size_t)n * 32 + 16 + row] = f2bf(t1);
    }
}

__global__ __launch_bounds__(256) void k_gemm0(
    const unsigned short* __restrict__ a0v, const unsigned short* __restrict__ wf0,
    const float* __restrict__ biasL, float* __restrict__ h,
    unsigned short* __restrict__ hbout) {
    int tid = threadIdx.x;
    int wid = tid >> 6, lane = tid & 63;
    int tile = blockIdx.x * 4 + wid;
    if (tile >= N_NODES / 16) return;
    int n0 = tile * 16;
    int row = lane & 15, kg = lane >> 4;
    half8 a = *(const half8*)(a0v + (size_t)(n0 + row) * 32 + kg * 8);
    const half8* wv = (const half8*)wf0;
    f32x4 c0 = {0.f, 0.f, 0.f, 0.f}, c1 = {0.f, 0.f, 0.f, 0.f};
    c0 = __builtin_amdgcn_mfma_f32_16x16x32_f16(a, wv[lane], c0, 0, 0, 0);
    c1 = __builtin_amdgcn_mfma_f32_16x16x32_f16(a, wv[64 + lane], c1, 0, 0, 0);
    float b0 = biasL[row], b1 = biasL[16 + row];
#pragma unroll
    for (int i = 0; i < 4; i++) {
        int n = n0 + kg * 4 + i;
        float t0 = tanhf(c0[i] + b0);
        float t1 = tanhf(c1[i] + b1);
        h[(size_t)n * 32 + row]      = t0;
        h[(size_t)n * 32 + 16 + row] = t1;
        hbout[(size_t)n * 32 + row]      = f2bf(t0);
        hbout[(size_t)n * 32 + 16 + row] = f2bf(t1);
    }
}

// ---------------- start-node row save + MLP head ----------------

__global__ void k_save(const float* __restrict__ h, const int* __restrict__ start,
                       float* __restrict__ sav) {
    int t = blockIdx.x * blockDim.x + threadIdx.x;
    if (t < B_START * 32) {
        int b = t >> 5, ln = t & 31;
        sav[t] = h[(size_t)start[b] * 32 + ln];
    }
}

__global__ __launch_bounds__(128) void k_mlp(
    const float* __restrict__ sav, const float* __restrict__ w1,
    const float* __restrict__ b1, const float* __restrict__ w2,
    const float* __restrict__ b2, float* __restrict__ out) {
    __shared__ float cvec[128];
    __shared__ float hb[128];
    __shared__ float lg[8];
    int b = blockIdx.x, t = threadIdx.x;
    cvec[t] = sav[(t >> 5) * (B_START * 32) + b * 32 + (t & 31)];
    __syncthreads();
    float a = b1[t];
#pragma unroll 8
    for (int k = 0; k < 128; k++) a += cvec[k] * w1[k * 128 + t];
    hb[t] = fmaxf(a, 0.f);
    __syncthreads();
    if (t < 5) {
        float a2 = b2[t];
        for (int k = 0; k < 128; k++) a2 += hb[k] * w2[k * 5 + t];
        lg[t] = a2;
    }
    __syncthreads();
    if (t < 5) {
        float m = lg[0];
        for (int j = 1; j < 5; j++) m = fmaxf(m, lg[j]);
        float s = 0.f;
        for (int j = 0; j < 5; j++) s += expf(lg[j] - m);
        out[b * 5 + t] = lg[t] - m - logf(s);
    }
}

// ---------------- launch ----------------

extern "C" void kernel_launch(void* const* d_in, const int* in_sizes, int n_in,
                              void* d_out, int out_size, void* d_ws, size_t ws_size,
                              hipStream_t stream) {
    const float* x      = (const float*)d_in[0];
    const int*   ei     = (const int*)d_in[1];
    const int*   etype  = (const int*)d_in[2];
    const int*   start  = (const int*)d_in[3];
    const float* basis0 = (const float*)d_in[4];
    const float* comp0  = (const float*)d_in[5];
    const float* root0  = (const float*)d_in[6];
    const float* bias0  = (const float*)d_in[7];
    const float* basis  = (const float*)d_in[8];
    const float* comp   = (const float*)d_in[9];
    const float* root   = (const float*)d_in[10];
    const float* bias   = (const float*)d_in[11];
    const float* w1     = (const float*)d_in[12];
    const float* b1     = (const float*)d_in[13];
    const float* w2     = (const float*)d_in[14];
    const float* b2     = (const float*)d_in[15];
    float* out = (float*)d_out;

    char* p = (char*)d_ws;
    auto alloc = [&](size_t bytes) -> void* {
        void* r = (void*)p;
        p += (bytes + 255) & ~(size_t)255;
        return r;
    };
    int*            bhist  = (int*)alloc((size_t)NBUCK * NBUCK * 4);
    int*            colsum = (int*)alloc(NBUCK * 4);
    int*            bbase  = (int*)alloc((NBUCK + 1) * 4);
    int*            arena  = (int*)alloc((size_t)N_EDGES * 4);
    int*            off    = (int*)alloc((N_NODES + 1) * 4);
    int*            pk_m   = (int*)alloc((size_t)N_EDGES * 4);
    float*          nv5    = (float*)alloc((size_t)N_NODES * R_REL * 4);
    unsigned*       degpk  = (unsigned*)alloc((size_t)N_NODES * 4);
    float*          h      = (float*)alloc((size_t)N_NODES * 32 * 4);
    unsigned short* hbuf   = (unsigned short*)alloc((size_t)(N_NODES + 64) * 32 * 2);
    unsigned short* hb0    = (unsigned short*)alloc((size_t)N_NODES * 4 * 2);
    unsigned short* a0v    = (unsigned short*)alloc((size_t)(N_NODES + 64) * 32 * 2);
    unsigned short* agg    = (unsigned short*)alloc((size_t)(N_NODES + 64) * 160 * 2);
    unsigned short* wfh    = (unsigned short*)alloc((size_t)3 * 5120 * 2);
    unsigned short* wfr    = (unsigned short*)alloc((size_t)3 * 2048 * 2);
    unsigned short* wf0    = (unsigned short*)alloc((size_t)1024 * 2);
    float*          sav    = (float*)alloc(4 * B_START * 32 * 4);

    k_cntb<<<NBUCK, 256, 0, stream>>>(ei, bhist);
    k_colscan<<<NBUCK, 256, 0, stream>>>(bhist, colsum);
    k_tiny<<<1, 256, 0, stream>>>(colsum, bbase);
    k_scat<<<NBUCK, 256, 0, stream>>>(ei, etype, bhist, bbase, arena);
    k_build<<<NBUCK, 256, 0, stream>>>(arena, bbase, off, pk_m, nv5, degpk);
    k_wprep<<<4, 256, 0, stream>>>(basis, comp, root, basis0, comp0, root0,
                                   wfh, wfr, wf0);
    k_cvt0<<<(N_NODES + 255) / 256, 256, 0, stream>>>(x, hb0);

    int nbGath = 8 * ((PART_SZ + 7) / 8);  // 12504 blocks (gath0)
    int nbGemm = (N_NODES / 16 + 3) / 4;   // 1563 blocks

    // layer 0 (in=4)
    k_gath0<<<nbGath, 256, 0, stream>>>(hb0, x, pk_m, nv5, degpk, off, a0v);
    k_gemm0<<<nbGemm, 256, 0, stream>>>(a0v, wf0, bias0, h, hbuf);
    k_save<<<64, 256, 0, stream>>>(h, start, sav);
    // layers 1..3 (in=32)
    for (int l = 0; l < 3; l++) {
        k_gath32<<<N_NODES / 32, 256, 0, stream>>>(hbuf, pk_m, nv5, degpk, off, agg);
        k_gemm<<<nbGemm, 256, 0, stream>>>(agg, hbuf, wfh + (size_t)l * 5120,
                                           wfr + (size_t)l * 2048, bias + l * 32,
                                           h, hbuf);
        k_save<<<64, 256, 0, stream>>>(h, start, sav + (l + 1) * 16384);
    }

    k_mlp<<<B_START, 128, 0, stream>>>(sav, w1, b1, w2, b2, out);
}

// Round 10
// 387.228 us; speedup vs baseline: 1.0595x; 1.0595x over previous
//
#include <hip/hip_runtime.h>
#include <cstdint>

#define N_NODES 100000
#define N_EDGES 1600000
#define R_REL   5
#define NBASIS  2
#define B_START 512
#define PART_SZ 12500     // 8 * 12500 = 100000 (gath0 swizzle)
#define NBUCK   256
#define BUCK_SZ 391       // 256 * 391 = 100096 >= 100000
#define EPB     6250      // edges per block in cnt/scat (256 * 6250 = 1.6M)
#define STAGE_CAP 7000    // bucket edge-count mean 6256, sd ~79
#define UNR     32        // flat-unroll edge cap (P[deg>32] ~ 1e-4)
#define NBLK32  3125      // gath32 gather blocks (32 nodes x 128 thr)

typedef __attribute__((ext_vector_type(8))) short short8;
typedef __attribute__((ext_vector_type(4))) float f32x4;
typedef _Float16 half8 __attribute__((ext_vector_type(8)));
typedef unsigned uint32x2 __attribute__((ext_vector_type(2)));
typedef unsigned uint32x4 __attribute__((ext_vector_type(4)));

__device__ __forceinline__ unsigned short f2bf(float f) {
    unsigned u = __float_as_uint(f);
    unsigned r = (u + 0x7FFF + ((u >> 16) & 1)) >> 16;  // RNE
    return (unsigned short)r;
}
__device__ __forceinline__ float bf2f(unsigned short u) {
    return __uint_as_float(((unsigned)u) << 16);
}
__device__ __forceinline__ unsigned short f2h(float f) {
    _Float16 h = (_Float16)f;                            // RNE
    return __builtin_bit_cast(unsigned short, h);
}

// ---------------- scatter-free CSR build ------------------------------------

__global__ __launch_bounds__(256) void k_cntb(
    const int* __restrict__ ei, int* __restrict__ bhist) {
    __shared__ int lh[NBUCK];
    int tid = threadIdx.x;
    lh[tid] = 0;
    __syncthreads();
    int base = blockIdx.x * EPB;
    for (int j = tid; j < EPB; j += 256) {
        int dst = ei[N_EDGES + base + j];
        atomicAdd(&lh[dst / BUCK_SZ], 1);
    }
    __syncthreads();
    bhist[blockIdx.x * NBUCK + tid] = lh[tid];
}

__global__ __launch_bounds__(256) void k_colscan(
    int* __restrict__ bhist, int* __restrict__ colsum) {
    __shared__ int s[256];
    int b = blockIdx.x, i = threadIdx.x;
    int v = bhist[i * NBUCK + b];
    s[i] = v;
    __syncthreads();
    for (int o = 1; o < 256; o <<= 1) {
        int t = (i >= o) ? s[i - o] : 0;
        __syncthreads();
        s[i] += t;
        __syncthreads();
    }
    bhist[i * NBUCK + b] = s[i] - v;
    if (i == 255) colsum[b] = s[255];
}

__global__ __launch_bounds__(256) void k_tiny(
    const int* __restrict__ colsum, int* __restrict__ bbase) {
    __shared__ int s[256];
    int i = threadIdx.x;
    int v = colsum[i];
    s[i] = v;
    __syncthreads();
    for (int o = 1; o < 256; o <<= 1) {
        int t = (i >= o) ? s[i - o] : 0;
        __syncthreads();
        s[i] += t;
        __syncthreads();
    }
    bbase[i] = s[i] - v;
    if (i == 255) bbase[NBUCK] = s[255];
}

// record = src | et<<17 | dst_local<<20
__global__ __launch_bounds__(256) void k_scat(
    const int* __restrict__ ei, const int* __restrict__ et,
    const int* __restrict__ bhist, const int* __restrict__ bbase,
    int* __restrict__ arena) {
    __shared__ int lc[NBUCK];
    int tid = threadIdx.x;
    lc[tid] = bhist[blockIdx.x * NBUCK + tid] + bbase[tid];
    __syncthreads();
    int base = blockIdx.x * EPB;
    for (int j = tid; j < EPB; j += 256) {
        int e   = base + j;
        int src = ei[e];
        int dst = ei[N_EDGES + e];
        int t   = et[e];
        int bk  = dst / BUCK_SZ;
        int dl  = dst - bk * BUCK_SZ;
        int pos = atomicAdd(&lc[bk], 1);
        arena[pos] = src | (t << 17) | (dl << 20);
    }
}

// builds (dst, et)-sorted CSR: pk_m = src per edge, degpk = packed 6-bit
// per-(dst,et) counts, nv5 = 1/max(cnt,1).
__global__ __launch_bounds__(256) void k_build(
    const int* __restrict__ arena, const int* __restrict__ bbase,
    int* __restrict__ off, int* __restrict__ pk_m, float* __restrict__ nv5,
    unsigned* __restrict__ degpk) {
    __shared__ int deg5[BUCK_SZ * R_REL];
    __shared__ int loff[BUCK_SZ + 1];
    __shared__ int cur5[BUCK_SZ * R_REL];
    __shared__ int stg[STAGE_CAP];
    __shared__ int tsum[256];
    int b = blockIdx.x, tid = threadIdx.x;
    int base = bbase[b], end = bbase[b + 1];
    int count = end - base;
    for (int i = tid; i < BUCK_SZ * R_REL; i += 256) deg5[i] = 0;
    __syncthreads();
    for (int i = tid; i < count; i += 256) {
        int r  = arena[base + i];
        int dl = ((unsigned)r) >> 20;
        int t  = (r >> 17) & 7;
        atomicAdd(&deg5[dl * R_REL + t], 1);
    }
    __syncthreads();
    for (int dl = tid; dl < BUCK_SZ; dl += 256) {
        loff[dl] = deg5[dl * R_REL + 0] + deg5[dl * R_REL + 1] +
                   deg5[dl * R_REL + 2] + deg5[dl * R_REL + 3] +
                   deg5[dl * R_REL + 4];
    }
    __syncthreads();
    int d0 = 2 * tid, d1 = 2 * tid + 1;
    int va = (d0 < BUCK_SZ) ? loff[d0] : 0;
    int vb = (d1 < BUCK_SZ) ? loff[d1] : 0;
    tsum[tid] = va + vb;
    __syncthreads();
    for (int o = 1; o < 256; o <<= 1) {
        int v = (tid >= o) ? tsum[tid - o] : 0;
        __syncthreads();
        tsum[tid] += v;
        __syncthreads();
    }
    int pre = tsum[tid] - (va + vb);
    if (d0 < BUCK_SZ) loff[d0] = pre;
    if (d1 < BUCK_SZ) loff[d1] = pre + va;
    __syncthreads();
    for (int dl = tid; dl < BUCK_SZ; dl += 256) {
        int nn = b * BUCK_SZ + dl;
        int run = loff[dl];
        unsigned dp = 0;
#pragma unroll
        for (int t = 0; t < R_REL; t++) {
            cur5[dl * R_REL + t] = run;
            int c = deg5[dl * R_REL + t];
            run += c;
            int cc = c > 63 ? 63 : c;
            dp |= ((unsigned)cc) << (6 * t);
        }
        if (nn < N_NODES) {
            off[nn]   = base + loff[dl];
            degpk[nn] = dp;
#pragma unroll
            for (int t = 0; t < R_REL; t++) {
                int c = deg5[dl * R_REL + t];
                nv5[nn * R_REL + t] = 1.0f / (float)(c > 0 ? c : 1);
            }
        }
    }
    if (b == NBUCK - 1 && tid == 0) off[N_NODES] = N_EDGES;
    __syncthreads();
    for (int i = tid; i < count; i += 256) {
        int r  = arena[base + i];
        int dl = ((unsigned)r) >> 20;
        int t  = (r >> 17) & 7;
        int rk = atomicAdd(&cur5[dl * R_REL + t], 1);
        if (rk < STAGE_CAP) stg[rk] = r;
    }
    __syncthreads();
    for (int i = tid; i < count; i += 256) {
        int r = stg[i < STAGE_CAP ? i : STAGE_CAP - 1];
        pk_m[base + i] = r & 0x1FFFF;     // src only; et implied by sort
    }
}

// ---------------- weight fragment prep (once, 4 blocks) ---------------------

__global__ __launch_bounds__(256) void k_wprep(
    const float* __restrict__ basis, const float* __restrict__ comp,
    const float* __restrict__ root,  const float* __restrict__ basis0,
    const float* __restrict__ comp0, const float* __restrict__ root0,
    unsigned short* __restrict__ wfh, unsigned short* __restrict__ wfr,
    unsigned short* __restrict__ wf0) {
    __shared__ float lw[5120];
    int tid = threadIdx.x;
    int l = blockIdx.x;
    if (l < 3) {
        for (int idx = tid; idx < 5120; idx += 256) {
            int r = idx >> 10, rem = idx & 1023, i = rem >> 5, o = rem & 31;
            lw[idx] = comp[l * 10 + r * 2 + 0] * basis[l * 2048 + i * 32 + o]
                    + comp[l * 10 + r * 2 + 1] * basis[l * 2048 + 1024 + i * 32 + o];
        }
        __syncthreads();
        for (int idx = tid; idx < 5120; idx += 256) {
            int ot = idx / 2560, rem = idx % 2560;
            int s = rem >> 9, ln = (rem >> 3) & 63, j = idx & 7;
            int o = ot * 16 + (ln & 15), kk = (ln >> 4) * 8 + j;
            wfh[l * 5120 + idx] = f2h(lw[s * 1024 + kk * 32 + o]);
        }
        for (int idx = tid; idx < 2048; idx += 256) {
            int ot = idx >> 10, s = (idx >> 9) & 1, ln = (idx >> 3) & 63, j = idx & 7;
            int o = ot * 16 + (ln & 15), kk = (ln >> 4) * 8 + j;
            float val = root[l * 1024 + kk * 32 + o];
            unsigned short hi = f2bf(val);
            wfr[l * 2048 + idx] = s ? f2bf(val - bf2f(hi)) : hi;
        }
    } else {
        for (int idx = tid; idx < 1024; idx += 256) {
            int k = idx >> 5, o = idx & 31;
            float val = 0.f;
            if (k < 20) {
                int r = k >> 2, i = k & 3;
                val = comp0[r * 2 + 0] * basis0[i * 32 + o]
                    + comp0[r * 2 + 1] * basis0[128 + i * 32 + o];
            } else if (k < 24) val = root0[(k - 20) * 32 + o];
            lw[idx] = val;
        }
        __syncthreads();
        for (int idx = tid; idx < 1024; idx += 256) {
            int ot = idx >> 9, ln = (idx >> 3) & 63, j = idx & 7;
            int o = ot * 16 + (ln & 15), kk = (ln >> 4) * 8 + j;
            wf0[idx] = f2h(lw[kk * 32 + o]);
        }
    }
}

// ---------------- gather (layers 1-3): flat-unroll, 4x16B per edge ----------
// 4 lanes per node (cpos = 16B chunk of the 64B row) — HALF the memory
// requests per edge vs round 9's 8x8B (final probe of the per-request
// floor). Same flat-MLP structure: 32 independent pk_m nt-loads, then 32
// independent row gathers; relation separation via position-masked FMAs.
// Save-blocks (blockIdx >= NBLK32) perform the previous layer's start-node
// row save (h is stable during this kernel) — folds k_save launches away.

__global__ __launch_bounds__(128) void k_gath32(
    const unsigned short* __restrict__ hb, const int* __restrict__ pk_m,
    const float* __restrict__ nv5, const unsigned* __restrict__ degpk,
    const int* __restrict__ off, unsigned short* __restrict__ agg,
    const float* __restrict__ h, const int* __restrict__ start,
    float* __restrict__ sav, int slot) {
    int tid = threadIdx.x;
    if (blockIdx.x >= NBLK32) {            // folded k_save (128 blocks x 128)
        int idx = (blockIdx.x - NBLK32) * 128 + tid;   // 0..16383
        int b = idx >> 5, ln = idx & 31;
        sav[(size_t)slot * 16384 + idx] = h[(size_t)start[b] * 32 + ln];
        return;
    }
    int n = blockIdx.x * 32 + (tid >> 2);  // 32 nodes per 128-thread block
    int cpos = tid & 3;                    // uint4 (8 ch) within 64B row
    const uint32x4* __restrict__ hb4 = (const uint32x4*)hb;

    int e0 = off[n];
    unsigned dp = degpk[n];
    int b1 = dp & 63;
    int b2 = b1 + ((dp >> 6) & 63);
    int b3 = b2 + ((dp >> 12) & 63);
    int b4 = b3 + ((dp >> 18) & 63);
    int deg = b4 + ((dp >> 24) & 63);
    float nv0 = nv5[n * R_REL + 0];
    float nv1 = nv5[n * R_REL + 1];
    float nv2 = nv5[n * R_REL + 2];
    float nv3 = nv5[n * R_REL + 3];
    float nv4 = nv5[n * R_REL + 4];

    int m[UNR];
#pragma unroll
    for (int k = 0; k < UNR; k++) {
        m[k] = 0;
        if (k < deg) m[k] = __builtin_nontemporal_load(pk_m + e0 + k);
    }

    float a[R_REL][8];
#pragma unroll
    for (int r = 0; r < R_REL; r++)
#pragma unroll
        for (int j = 0; j < 8; j++) a[r][j] = 0.f;

#pragma unroll
    for (int k = 0; k < UNR; k++) {
        if (k < deg) {
            uint32x4 u = hb4[(size_t)m[k] * 4 + cpos];
            float v[8];
            v[0] = __uint_as_float(u.x << 16);
            v[1] = __uint_as_float(u.x & 0xFFFF0000u);
            v[2] = __uint_as_float(u.y << 16);
            v[3] = __uint_as_float(u.y & 0xFFFF0000u);
            v[4] = __uint_as_float(u.z << 16);
            v[5] = __uint_as_float(u.z & 0xFFFF0000u);
            v[6] = __uint_as_float(u.w << 16);
            v[7] = __uint_as_float(u.w & 0xFFFF0000u);
            float w[R_REL];
            w[0] = (k < b1) ? nv0 : 0.f;
            w[1] = (k >= b1 && k < b2) ? nv1 : 0.f;
            w[2] = (k >= b2 && k < b3) ? nv2 : 0.f;
            w[3] = (k >= b3 && k < b4) ? nv3 : 0.f;
            w[4] = (k >= b4) ? nv4 : 0.f;
#pragma unroll
            for (int r = 0; r < R_REL; r++)
#pragma unroll
                for (int j = 0; j < 8; j++) a[r][j] += w[r] * v[j];
        }
    }
    for (int k = UNR; k < deg; k++) {        // rare tail
        int mk = __builtin_nontemporal_load(pk_m + e0 + k);
        uint32x4 u = hb4[(size_t)mk * 4 + cpos];
        float v[8];
        v[0] = __uint_as_float(u.x << 16);
        v[1] = __uint_as_float(u.x & 0xFFFF0000u);
        v[2] = __uint_as_float(u.y << 16);
        v[3] = __uint_as_float(u.y & 0xFFFF0000u);
        v[4] = __uint_as_float(u.z << 16);
        v[5] = __uint_as_float(u.z & 0xFFFF0000u);
        v[6] = __uint_as_float(u.w << 16);
        v[7] = __uint_as_float(u.w & 0xFFFF0000u);
        float w[R_REL];
        w[0] = (k < b1) ? nv0 : 0.f;
        w[1] = (k >= b1 && k < b2) ? nv1 : 0.f;
        w[2] = (k >= b2 && k < b3) ? nv2 : 0.f;
        w[3] = (k >= b3 && k < b4) ? nv3 : 0.f;
        w[4] = (k >= b4) ? nv4 : 0.f;
#pragma unroll
        for (int r = 0; r < R_REL; r++)
#pragma unroll
            for (int j = 0; j < 8; j++) a[r][j] += w[r] * v[j];
    }
#pragma unroll
    for (int r = 0; r < R_REL; r++) {
        uint32x4 pk;
        pk.x = (unsigned)f2h(a[r][0]) | ((unsigned)f2h(a[r][1]) << 16);
        pk.y = (unsigned)f2h(a[r][2]) | ((unsigned)f2h(a[r][3]) << 16);
        pk.z = (unsigned)f2h(a[r][4]) | ((unsigned)f2h(a[r][5]) << 16);
        pk.w = (unsigned)f2h(a[r][6]) | ((unsigned)f2h(a[r][7]) << 16);
        __builtin_nontemporal_store(pk,
            (uint32x4*)(agg + (size_t)n * 160 + r * 32 + cpos * 8));
    }
}

// gather layer 0 (IN=4): wave-parallel (R4-verified shape) reading x (f32)
// DIRECTLY — no bf16 staging table. lane = slot(4b)*2 + cpos(1b); 16 edges
// in flight, float2 (8B, half of the 16B row) loads. Also fills x (f16) +
// zero pad cols 20-31 of the [n][32] A-row.

__global__ __launch_bounds__(256) void k_gath0(
    const float* __restrict__ x, const int* __restrict__ pk_m,
    const float* __restrict__ nv5, const unsigned* __restrict__ degpk,
    const int* __restrict__ off, unsigned short* __restrict__ a0v) {
    int tid  = threadIdx.x;
    int lane32 = tid & 31;
    int sub  = tid >> 5;
    int part  = blockIdx.x & 7;
    int local = (blockIdx.x >> 3) * 8 + sub;
    if (local >= PART_SZ) return;
    int n = part * PART_SZ + local;
    int cpos = lane32 & 1;
    int slot = lane32 >> 1;
    const float2* __restrict__ x2 = (const float2*)x;

    int e0 = off[n];
    unsigned dp = degpk[n];
    int chunkbase = e0;
    int mreg = (chunkbase + lane32 < N_EDGES)
             ? __builtin_nontemporal_load(pk_m + chunkbase + lane32) : 0;
    int e = e0;
#pragma unroll
    for (int r = 0; r < R_REL; r++) {
        int cnt = (int)((dp >> (6 * r)) & 63u);
        float nv = nv5[n * R_REL + r];
        float p0 = 0.f, p1 = 0.f;
        for (int kb = 0; kb < cnt; kb += 16) {
            if (e + kb + 15 >= chunkbase + 32) {
                chunkbase = e + kb;
                mreg = (chunkbase + lane32 < N_EDGES)
                     ? __builtin_nontemporal_load(pk_m + chunkbase + lane32) : 0;
            }
            int kq = kb + slot;
            int mq = __shfl(mreg, e + kq - chunkbase, 32);
            float2 u = x2[(size_t)mq * 2 + cpos];
            float msk = (kq < cnt) ? nv : 0.f;
            p0 += msk * u.x;
            p1 += msk * u.y;
        }
        e += cnt;
        p0 += __shfl_xor(p0, 2, 32); p0 += __shfl_xor(p0, 4, 32);
        p0 += __shfl_xor(p0, 8, 32); p0 += __shfl_xor(p0, 16, 32);
        p1 += __shfl_xor(p1, 2, 32); p1 += __shfl_xor(p1, 4, 32);
        p1 += __shfl_xor(p1, 8, 32); p1 += __shfl_xor(p1, 16, 32);
        if (slot == 0) {
            unsigned pk = (unsigned)f2h(p0) | ((unsigned)f2h(p1) << 16);
            *(unsigned*)(a0v + (size_t)n * 32 + r * 4 + cpos * 2) = pk;
        }
    }
    if (lane32 < 12) {
        float xv = (lane32 < 4) ? x[(size_t)n * 4 + lane32] : 0.f;
        a0v[(size_t)n * 32 + 20 + lane32] = (lane32 < 4) ? f2h(xv) : (unsigned short)0;
    }
}

// ---------------- dense relation transform via MFMA -------------------------
// h[n][o] = tanh( sum_r agg_r W_r (f16) + hb_prev root (double-bf16) + bias ).
// A-frag: row = lane%16, k = (lane/16)*8+j.  C: col = lane%16,
// row = (lane/16)*4+reg.  In-place hbuf write is race-free (wave-local tile).

__global__ __launch_bounds__(256) void k_gemm(
    const unsigned short* __restrict__ agg, const unsigned short* __restrict__ hbin,
    const unsigned short* __restrict__ wfhl, const unsigned short* __restrict__ wfrl,
    const float* __restrict__ biasL, float* __restrict__ h,
    unsigned short* __restrict__ hbout) {
    int tid = threadIdx.x;
    int wid = tid >> 6, lane = tid & 63;
    int tile = blockIdx.x * 4 + wid;
    if (tile >= N_NODES / 16) return;
    int n0 = tile * 16;
    int row = lane & 15, kg = lane >> 4;
    const half8* ar = (const half8*)(agg + (size_t)(n0 + row) * 160 + kg * 8);
    const half8* wh = (const half8*)wfhl;
    const short8* wr = (const short8*)wfrl;
    short8 hbf = *(const short8*)(hbin + (size_t)(n0 + row) * 32 + kg * 8);
    f32x4 c0 = {0.f, 0.f, 0.f, 0.f}, c1 = {0.f, 0.f, 0.f, 0.f};
#pragma unroll
    for (int s = 0; s < 5; s++) {
        half8 a = __builtin_nontemporal_load(&ar[s * 4]);
        c0 = __builtin_amdgcn_mfma_f32_16x16x32_f16(a, wh[s * 64 + lane], c0, 0, 0, 0);
        c1 = __builtin_amdgcn_mfma_f32_16x16x32_f16(a, wh[320 + s * 64 + lane], c1, 0, 0, 0);
    }
    c0 = __builtin_amdgcn_mfma_f32_16x16x32_bf16(hbf, wr[lane], c0, 0, 0, 0);
    c0 = __builtin_amdgcn_mfma_f32_16x16x32_bf16(hbf, wr[64 + lane], c0, 0, 0, 0);
    c1 = __builtin_amdgcn_mfma_f32_16x16x32_bf16(hbf, wr[128 + lane], c1, 0, 0, 0);
    c1 = __builtin_amdgcn_mfma_f32_16x16x32_bf16(hbf, wr[192 + lane], c1, 0, 0, 0);
    float b0 = biasL[row], b1 = biasL[16 + row];
#pragma unroll
    for (int i = 0; i < 4; i++) {
        int n = n0 + kg * 4 + i;
        float t0 = tanhf(c0[i] + b0);
        float t1 = tanhf(c1[i] + b1);
        h[(size_t)n * 32 + row]      = t0;
        h[(size_t)n * 32 + 16 + row] = t1;
        hbout[(size_t)n * 32 + row]      = f2bf(t0);
        hbout[(size_t)n * 32 + 16 + row] = f2bf(t1);
    }
}

__global__ __launch_bounds__(256) void k_gemm0(
    const unsigned short* __restrict__ a0v, const unsigned short* __restrict__ wf0,
    const float* __restrict__ biasL, float* __restrict__ h,
    unsigned short* __restrict__ hbout) {
    int tid = threadIdx.x;
    int wid = tid >> 6, lane = tid & 63;
    int tile = blockIdx.x * 4 + wid;
    if (tile >= N_NODES / 16) return;
    int n0 = tile * 16;
    int row = lane & 15, kg = lane >> 4;
    half8 a = *(const half8*)(a0v + (size_t)(n0 + row) * 32 + kg * 8);
    const half8* wv = (const half8*)wf0;
    f32x4 c0 = {0.f, 0.f, 0.f, 0.f}, c1 = {0.f, 0.f, 0.f, 0.f};
    c0 = __builtin_amdgcn_mfma_f32_16x16x32_f16(a, wv[lane], c0, 0, 0, 0);
    c1 = __builtin_amdgcn_mfma_f32_16x16x32_f16(a, wv[64 + lane], c1, 0, 0, 0);
    float b0 = biasL[row], b1 = biasL[16 + row];
#pragma unroll
    for (int i = 0; i < 4; i++) {
        int n = n0 + kg * 4 + i;
        float t0 = tanhf(c0[i] + b0);
        float t1 = tanhf(c1[i] + b1);
        h[(size_t)n * 32 + row]      = t0;
        h[(size_t)n * 32 + 16 + row] = t1;
        hbout[(size_t)n * 32 + row]      = f2bf(t0);
        hbout[(size_t)n * 32 + 16 + row] = f2bf(t1);
    }
}

// ---------------- MLP head (layers 0-2 from sav, layer 3 direct from h) -----

__global__ __launch_bounds__(128) void k_mlp(
    const float* __restrict__ sav, const float* __restrict__ h,
    const int* __restrict__ start, const float* __restrict__ w1,
    const float* __restrict__ b1, const float* __restrict__ w2,
    const float* __restrict__ b2, float* __restrict__ out) {
    __shared__ float cvec[128];
    __shared__ float hb[128];
    __shared__ float lg[8];
    int b = blockIdx.x, t = threadIdx.x;
    int l = t >> 5, ln = t & 31;
    cvec[t] = (l < 3) ? sav[l * (B_START * 32) + b * 32 + ln]
                      : h[(size_t)start[b] * 32 + ln];
    __syncthreads();
    float a = b1[t];
#pragma unroll 8
    for (int k = 0; k < 128; k++) a += cvec[k] * w1[k * 128 + t];
    hb[t] = fmaxf(a, 0.f);
    __syncthreads();
    if (t < 5) {
        float a2 = b2[t];
        for (int k = 0; k < 128; k++) a2 += hb[k] * w2[k * 5 + t];
        lg[t] = a2;
    }
    __syncthreads();
    if (t < 5) {
        float m = lg[0];
        for (int j = 1; j < 5; j++) m = fmaxf(m, lg[j]);
        float s = 0.f;
        for (int j = 0; j < 5; j++) s += expf(lg[j] - m);
        out[b * 5 + t] = lg[t] - m - logf(s);
    }
}

// ---------------- launch ----------------

extern "C" void kernel_launch(void* const* d_in, const int* in_sizes, int n_in,
                              void* d_out, int out_size, void* d_ws, size_t ws_size,
                              hipStream_t stream) {
    const float* x      = (const float*)d_in[0];
    const int*   ei     = (const int*)d_in[1];
    const int*   etype  = (const int*)d_in[2];
    const int*   start  = (const int*)d_in[3];
    const float* basis0 = (const float*)d_in[4];
    const float* comp0  = (const float*)d_in[5];
    const float* root0  = (const float*)d_in[6];
    const float* bias0  = (const float*)d_in[7];
    const float* basis  = (const float*)d_in[8];
    const float* comp   = (const float*)d_in[9];
    const float* root   = (const float*)d_in[10];
    const float* bias   = (const float*)d_in[11];
    const float* w1     = (const float*)d_in[12];
    const float* b1     = (const float*)d_in[13];
    const float* w2     = (const float*)d_in[14];
    const float* b2     = (const float*)d_in[15];
    float* out = (float*)d_out;

    char* p = (char*)d_ws;
    auto alloc = [&](size_t bytes) -> void* {
        void* r = (void*)p;
        p += (bytes + 255) & ~(size_t)255;
        return r;
    };
    int*            bhist  = (int*)alloc((size_t)NBUCK * NBUCK * 4);
    int*            colsum = (int*)alloc(NBUCK * 4);
    int*            bbase  = (int*)alloc((NBUCK + 1) * 4);
    int*            arena  = (int*)alloc((size_t)N_EDGES * 4);
    int*            off    = (int*)alloc((N_NODES + 1) * 4);
    int*            pk_m   = (int*)alloc((size_t)N_EDGES * 4);
    float*          nv5    = (float*)alloc((size_t)N_NODES * R_REL * 4);
    unsigned*       degpk  = (unsigned*)alloc((size_t)N_NODES * 4);
    float*          h      = (float*)alloc((size_t)N_NODES * 32 * 4);
    unsigned short* hbuf   = (unsigned short*)alloc((size_t)(N_NODES + 64) * 32 * 2);
    unsigned short* a0v    = (unsigned short*)alloc((size_t)(N_NODES + 64) * 32 * 2);
    unsigned short* agg    = (unsigned short*)alloc((size_t)(N_NODES + 64) * 160 * 2);
    unsigned short* wfh    = (unsigned short*)alloc((size_t)3 * 5120 * 2);
    unsigned short* wfr    = (unsigned short*)alloc((size_t)3 * 2048 * 2);
    unsigned short* wf0    = (unsigned short*)alloc((size_t)1024 * 2);
    float*          sav    = (float*)alloc(4 * B_START * 32 * 4);

    k_cntb<<<NBUCK, 256, 0, stream>>>(ei, bhist);
    k_colscan<<<NBUCK, 256, 0, stream>>>(bhist, colsum);
    k_tiny<<<1, 256, 0, stream>>>(colsum, bbase);
    k_scat<<<NBUCK, 256, 0, stream>>>(ei, etype, bhist, bbase, arena);
    k_build<<<NBUCK, 256, 0, stream>>>(arena, bbase, off, pk_m, nv5, degpk);
    k_wprep<<<4, 256, 0, stream>>>(basis, comp, root, basis0, comp0, root0,
                                   wfh, wfr, wf0);

    int nbGath0 = 8 * ((PART_SZ + 7) / 8);  // 12504 blocks (gath0)
    int nbGemm  = (N_NODES / 16 + 3) / 4;   // 1563 blocks
    int nbG32   = NBLK32 + 128;             // 3125 gather + 128 save blocks

    // layer 0 (in=4)
    k_gath0<<<nbGath0, 256, 0, stream>>>(x, pk_m, nv5, degpk, off, a0v);
    k_gemm0<<<nbGemm, 256, 0, stream>>>(a0v, wf0, bias0, h, hbuf);
    // layers 1..3 (in=32); gath32 also saves the previous layer's rows
    for (int l = 0; l < 3; l++) {
        k_gath32<<<nbG32, 128, 0, stream>>>(hbuf, pk_m, nv5, degpk, off, agg,
                                            h, start, sav, l);
        k_gemm<<<nbGemm, 256, 0, stream>>>(agg, hbuf, wfh + (size_t)l * 5120,
                                           wfr + (size_t)l * 2048, bias + l * 32,
                                           h, hbuf);
    }

    k_mlp<<<B_START, 128, 0, stream>>>(sav, h, start, w1, b1, w2, b2, out);
}